// Round 7
// baseline (284.651 us; speedup 1.0000x reference)
//
#include <hip/hip_runtime.h>
#include <hip/hip_bf16.h>

// Problem dims (fixed by setup_inputs): B=64, N=16384, D=1024, A=2048, H=8
#define NB 64
#define NN 16384
#define ND 1024
#define NA 2048
#define NH 8
#define KSPL 64     // k_post split-K chunks
#define NPL 16      // h_part planes (= NA/128 n-blocks of k_c1h)
#define MAXL 1024   // max cached segment length in k_seg

typedef __attribute__((ext_vector_type(4))) float f32x4;
typedef __attribute__((ext_vector_type(8))) short short8;
typedef __attribute__((ext_vector_type(8))) unsigned short ushort8;

__device__ __forceinline__ unsigned short f2bf(float f) {
    unsigned int u = __float_as_uint(f);
    u = (u + 0x7fff + ((u >> 16) & 1)) >> 16;   // round-to-nearest-even
    return (unsigned short)u;
}

__device__ __forceinline__ float bf2f(unsigned short s) {
    return __uint_as_float((unsigned int)s << 16);
}

__device__ __forceinline__ void load_lds16(const void* g, void* l) {
    __builtin_amdgcn_global_load_lds((const __attribute__((address_space(1))) void*)g,
                                     (__attribute__((address_space(3))) void*)l, 16, 0, 0);
}

// sum of the NPL h partial planes for frame n -> v[8]
__device__ __forceinline__ void hsum_row(const float* __restrict__ h_part, int n, float* v) {
#pragma unroll
    for (int q = 0; q < NH; q++) v[q] = 0.f;
#pragma unroll
    for (int p = 0; p < NPL; p++) {
        const float4* hp = (const float4*)(h_part + (size_t)p * (NN * NH) + (size_t)n * NH);
        float4 u0 = hp[0], u1 = hp[1];
        v[0] += u0.x; v[1] += u0.y; v[2] += u0.z; v[3] += u0.w;
        v[4] += u1.x; v[5] += u1.y; v[6] += u1.z; v[7] += u1.w;
    }
}

// ---- k_pre: segoff + cast x->xb + cast/transpose w1->w1t
__global__ __launch_bounds__(256) void k_pre(const float* __restrict__ x,
                                             const float* __restrict__ w1,
                                             const int* __restrict__ segnum,
                                             unsigned short* __restrict__ xb,
                                             unsigned short* __restrict__ w1t,
                                             int* __restrict__ segoff) {
    __shared__ unsigned short t[32][33];
    const int bx = blockIdx.x;
    if (bx < 8192) {
        size_t i = ((size_t)bx * 256 + threadIdx.x) * 8;
        float4 a = *(const float4*)(x + i);
        float4 b = *(const float4*)(x + i + 4);
        ushort8 o;
        o[0] = f2bf(a.x); o[1] = f2bf(a.y); o[2] = f2bf(a.z); o[3] = f2bf(a.w);
        o[4] = f2bf(b.x); o[5] = f2bf(b.y); o[6] = f2bf(b.z); o[7] = f2bf(b.w);
        *(ushort8*)(xb + i) = o;
    } else if (bx < 10240) {
        const int idx = bx - 8192;                 // 0..2047
        const int a0 = (idx & 63) * 32, d0 = (idx >> 6) * 32;
        const int tx = threadIdx.x & 31, ty4 = (threadIdx.x >> 5) * 4;
#pragma unroll
        for (int i = 0; i < 4; i++)
            t[tx][ty4 + i] = f2bf(w1[(size_t)(d0 + ty4 + i) * NA + a0 + tx]);
        __syncthreads();
#pragma unroll
        for (int i = 0; i < 4; i++)
            w1t[(size_t)(a0 + ty4 + i) * ND + d0 + tx] = t[ty4 + i][tx];
    } else {
        if (threadIdx.x == 0) {
            int a = 0;
            segoff[0] = 0;
            for (int b = 0; b < NB; b++) { a += segnum[b]; segoff[b + 1] = a; }
        }
    }
}

// --- k_c1h: c1 = relu(xb @ w1t^T) tile kept in LDS; h_part[by] = tile @ w2slice
// grid (N/128, A/128), block 256 (4 waves, 2x2 wave grid, 64x64 per wave)
__global__ __launch_bounds__(256) void k_c1h(const unsigned short* __restrict__ xb,
                                             const unsigned short* __restrict__ w1t,
                                             const float* __restrict__ w2,
                                             float* __restrict__ h_part) {
    __shared__ unsigned short SM[21760];           // 43.5KB
    unsigned short* As  = SM;                      // [128*64] (main loop)
    unsigned short* Bs  = SM + 8192;               // [128*64]
    unsigned short* c1s = SM;                      // [128][136] (epilogue, overlaps As/Bs)
    unsigned short* w2hi = SM + 17408;             // [16][136]
    unsigned short* w2lo = SM + 19584;             // [16][136]

    const int tid = threadIdx.x;
    const int wave = tid >> 6, lane = tid & 63;
    const int wm = wave & 1, wn = wave >> 1;
    const int m0 = blockIdx.x * 128, n0 = blockIdx.y * 128;
    const int quad = lane >> 4, lc = lane & 15;

    // stage w2 slice -> transposed bf16 hi/lo planes [q(16, rows 8..15 = 0)][k(128)]
    for (int i = tid; i < 2176; i += 256) { w2hi[i] = 0; w2lo[i] = 0; }
    for (int i = tid; i < 1024; i += 256) {
        int k = i >> 3, q = i & 7;
        float w = w2[(size_t)(n0 + k) * NH + q];
        unsigned short hi = f2bf(w);
        w2hi[q * 136 + k] = hi;
        w2lo[q * 136 + k] = f2bf(w - bf2f(hi));
    }

    f32x4 acc[4][4];
#pragma unroll
    for (int i = 0; i < 4; i++)
#pragma unroll
        for (int j = 0; j < 4; j++) acc[i][j] = (f32x4){0.f, 0.f, 0.f, 0.f};

    const int srow = lane >> 3;           // 0..7 within issue
    const int sg = lane & 7;              // logical granule 0..7 (8 bf16 each)

    for (int k0 = 0; k0 < ND; k0 += 64) {
        __syncthreads();
#pragma unroll
        for (int i = 0; i < 4; i++) {
            int r = wave * 32 + i * 8 + srow;
            int gc = (sg ^ (r & 7)) * 8;  // swizzled global column (bf16 units)
            load_lds16(xb + (size_t)(m0 + r) * ND + k0 + gc, As + r * 64 + sg * 8);
            load_lds16(w1t + (size_t)(n0 + r) * ND + k0 + gc, Bs + r * 64 + sg * 8);
        }
        __syncthreads();
#pragma unroll
        for (int ksub = 0; ksub < 2; ksub++) {
            short8 af[4], bf[4];
            const int lg = ksub * 4 + quad;
#pragma unroll
            for (int t = 0; t < 4; t++) {
                int m = wm * 64 + t * 16 + lc;
                af[t] = *(const short8*)&As[m * 64 + (lg ^ (m & 7)) * 8];
                int n = wn * 64 + t * 16 + lc;
                bf[t] = *(const short8*)&Bs[n * 64 + (lg ^ (n & 7)) * 8];
            }
#pragma unroll
            for (int mi = 0; mi < 4; mi++)
#pragma unroll
                for (int ni = 0; ni < 4; ni++)
                    acc[mi][ni] = __builtin_amdgcn_mfma_f32_16x16x32_bf16(
                        af[mi], bf[ni], acc[mi][ni], 0, 0, 0);
        }
    }

    // ---- epilogue: relu tile -> LDS (bf16), then tile @ w2slice via MFMA
    __syncthreads();   // all As/Bs readers done before c1s overwrite
#pragma unroll
    for (int mi = 0; mi < 4; mi++)
#pragma unroll
        for (int ni = 0; ni < 4; ni++) {
            const int col = wn * 64 + ni * 16 + lc;
#pragma unroll
            for (int r = 0; r < 4; r++) {
                const int row = wm * 64 + mi * 16 + quad * 4 + r;
                c1s[row * 136 + col] = f2bf(fmaxf(acc[mi][ni][r], 0.f));
            }
        }
    __syncthreads();

    // wave handles rows wave*32 .. +31 (2 M-tiles), K = 128 (4 steps), hi+lo B
    f32x4 hacc[2];
    hacc[0] = (f32x4){0.f, 0.f, 0.f, 0.f};
    hacc[1] = (f32x4){0.f, 0.f, 0.f, 0.f};
#pragma unroll
    for (int ks = 0; ks < 4; ks++) {
        short8 bh = *(const short8*)&w2hi[lc * 136 + ks * 32 + quad * 8];
        short8 bl = *(const short8*)&w2lo[lc * 136 + ks * 32 + quad * 8];
#pragma unroll
        for (int mt = 0; mt < 2; mt++) {
            short8 af = *(const short8*)&c1s[(wave * 32 + mt * 16 + lc) * 136 + ks * 32 + quad * 8];
            hacc[mt] = __builtin_amdgcn_mfma_f32_16x16x32_bf16(af, bh, hacc[mt], 0, 0, 0);
            hacc[mt] = __builtin_amdgcn_mfma_f32_16x16x32_bf16(af, bl, hacc[mt], 0, 0, 0);
        }
    }

    if (lc < NH) {
        float* hp = h_part + (size_t)blockIdx.y * (NN * NH);
#pragma unroll
        for (int mt = 0; mt < 2; mt++)
#pragma unroll
            for (int r = 0; r < 4; r++)
                hp[(size_t)(m0 + wave * 32 + mt * 16 + quad * 4 + r) * NH + lc] = hacc[mt][r];
    }
}

// ---- k_seg: per (segment, 128-d-chunk): h-plane-sum -> softmax (LDS) -> attn
//      (in-place LDS) -> gram (dc==0) -> bdh slice + out_segment. No globals
//      between stages, no atomics.
__global__ __launch_bounds__(256) void k_seg(const float* __restrict__ h_part,
                                             const unsigned short* __restrict__ xb,
                                             const int* __restrict__ segoff,
                                             float* __restrict__ bdh,
                                             float* __restrict__ out_segment,
                                             float* __restrict__ gram) {
    const int dc = blockIdx.x;            // 0..7 (128 d each)
    const int b  = blockIdx.y;
    const int s0 = segoff[b], s1 = segoff[b + 1];
    const int len = s1 - s0;
    const int cap = len < MAXL ? len : MAXL;
    const int tid = threadIdx.x;
    const int wv = tid >> 6;

    __shared__ float hl[MAXL * NH];       // 32KB: summed h, then attn in place
    __shared__ float redf[8 * 32 * 33];   // 33KB: fo-reduction (pad 33 vs bank conflicts)
    __shared__ float xsred[8][132];
    __shared__ float red[4][NH], mb[NH], sinv[NH], gred[4][64];

    // phase 0: hl[r][q] = sum_p h_part[p][s0+r][q]   (rows < MAXL)
    for (int i = tid; i < cap * 2; i += 256) {        // float4 units
        float4 s = make_float4(0.f, 0.f, 0.f, 0.f);
#pragma unroll
        for (int p = 0; p < NPL; p++) {
            float4 u = *((const float4*)(h_part + (size_t)p * (NN * NH)) + (size_t)s0 * 2 + i);
            s.x += u.x; s.y += u.y; s.z += u.z; s.w += u.w;
        }
        ((float4*)hl)[i] = s;
    }
    __syncthreads();

    // pass 1: max
    float mx[NH];
#pragma unroll
    for (int q = 0; q < NH; q++) mx[q] = -1e30f;
    for (int r = tid; r < len; r += 256) {
        float v[NH];
        if (r < MAXL) {
#pragma unroll
            for (int q = 0; q < NH; q++) v[q] = hl[r * NH + q];
        } else hsum_row(h_part, s0 + r, v);
#pragma unroll
        for (int q = 0; q < NH; q++) mx[q] = fmaxf(mx[q], v[q]);
    }
#pragma unroll
    for (int q = 0; q < NH; q++)
        for (int o = 1; o < 64; o <<= 1) mx[q] = fmaxf(mx[q], __shfl_xor(mx[q], o));
    if ((tid & 63) == 0)
        for (int q = 0; q < NH; q++) red[wv][q] = mx[q];
    __syncthreads();
    if (tid < NH)
        mb[tid] = fmaxf(fmaxf(red[0][tid], red[1][tid]), fmaxf(red[2][tid], red[3][tid]));
    __syncthreads();

    // pass 2: sum of exp
    float sm[NH];
#pragma unroll
    for (int q = 0; q < NH; q++) sm[q] = 0.f;
    for (int r = tid; r < len; r += 256) {
        float v[NH];
        if (r < MAXL) {
#pragma unroll
            for (int q = 0; q < NH; q++) v[q] = hl[r * NH + q];
        } else hsum_row(h_part, s0 + r, v);
#pragma unroll
        for (int q = 0; q < NH; q++) sm[q] += expf(v[q] - mb[q]);
    }
#pragma unroll
    for (int q = 0; q < NH; q++)
        for (int o = 1; o < 64; o <<= 1) sm[q] += __shfl_xor(sm[q], o);
    if ((tid & 63) == 0)
        for (int q = 0; q < NH; q++) red[wv][q] = sm[q];
    __syncthreads();
    if (tid < NH)
        sinv[tid] = 1.0f / (red[0][tid] + red[1][tid] + red[2][tid] + red[3][tid]);
    __syncthreads();

    // pass 3: attn in place in LDS
    for (int r = tid; r < cap; r += 256) {
#pragma unroll
        for (int q = 0; q < NH; q++)
            hl[r * NH + q] = expf(hl[r * NH + q] - mb[q]) * sinv[q];
    }
    __syncthreads();

    // gram (only dc==0 block)
    if (dc == 0) {
        float g[NH][NH];
#pragma unroll
        for (int i = 0; i < NH; i++)
#pragma unroll
            for (int j = 0; j < NH; j++) g[i][j] = 0.f;
        for (int r = tid; r < len; r += 256) {
            float a[NH];
            if (r < MAXL) {
#pragma unroll
                for (int q = 0; q < NH; q++) a[q] = hl[r * NH + q];
            } else {
                hsum_row(h_part, s0 + r, a);
#pragma unroll
                for (int q = 0; q < NH; q++) a[q] = expf(a[q] - mb[q]) * sinv[q];
            }
#pragma unroll
            for (int i = 0; i < NH; i++)
#pragma unroll
                for (int j = 0; j < NH; j++) g[i][j] += a[i] * a[j];
        }
#pragma unroll
        for (int i = 0; i < NH; i++)
#pragma unroll
            for (int j = 0; j < NH; j++)
                for (int o = 1; o < 64; o <<= 1) g[i][j] += __shfl_xor(g[i][j], o);
        if ((tid & 63) == 0) {
#pragma unroll
            for (int i = 0; i < NH; i++)
#pragma unroll
                for (int j = 0; j < NH; j++) gred[wv][i * NH + j] = g[i][j];
        }
        __syncthreads();
        if (tid < 64)
            gram[(size_t)b * 64 + tid] = gred[0][tid] + gred[1][tid] + gred[2][tid] + gred[3][tid];
    }

    // bdh slice: thread = (fo 0..7, dg 0..31), owns 4 d-cols
    const int fo = tid >> 5, dg = tid & 31;
    const int d = dc * 128 + dg * 4;
    float acc[4][NH];
    float xs4[4] = {0.f, 0.f, 0.f, 0.f};
#pragma unroll
    for (int dd = 0; dd < 4; dd++)
#pragma unroll
        for (int q = 0; q < NH; q++) acc[dd][q] = 0.f;

    for (int n = fo; n < len; n += 8) {
        ushort4 xv = *(const ushort4*)(xb + (size_t)(s0 + n) * ND + d);
        float a[NH];
        if (n < MAXL) {
            const float4* ap = (const float4*)&hl[n * NH];
            float4 a0 = ap[0], a1 = ap[1];
            a[0] = a0.x; a[1] = a0.y; a[2] = a0.z; a[3] = a0.w;
            a[4] = a1.x; a[5] = a1.y; a[6] = a1.z; a[7] = a1.w;
        } else {
            hsum_row(h_part, s0 + n, a);
#pragma unroll
            for (int q = 0; q < NH; q++) a[q] = expf(a[q] - mb[q]) * sinv[q];
        }
        float xf[4] = {bf2f(xv.x), bf2f(xv.y), bf2f(xv.z), bf2f(xv.w)};
#pragma unroll
        for (int dd = 0; dd < 4; dd++) {
            xs4[dd] += xf[dd];
#pragma unroll
            for (int q = 0; q < NH; q++) acc[dd][q] += xf[dd] * a[q];
        }
    }

    // reduce over the 8 fo slots through padded LDS
    {
        float* rp = redf + (fo * 32 + dg) * 33;
#pragma unroll
        for (int dd = 0; dd < 4; dd++)
#pragma unroll
            for (int q = 0; q < NH; q++) rp[dd * 8 + q] = acc[dd][q];
#pragma unroll
        for (int dd = 0; dd < 4; dd++) xsred[fo][dg * 4 + dd] = xs4[dd];
    }
    __syncthreads();
    {
        // 1024 (d,h) outputs; thread t handles o = 4t..4t+3
        float ov[4];
#pragma unroll
        for (int j = 0; j < 4; j++) {
            int o = tid * 4 + j;
            int g = o >> 5, e = o & 31;
            float s = 0.f;
#pragma unroll
            for (int f = 0; f < 8; f++) s += redf[(f * 32 + g) * 33 + e];
            ov[j] = s;
        }
        *(float4*)(bdh + (size_t)b * (ND * NH) + (size_t)dc * 1024 + tid * 4) =
            make_float4(ov[0], ov[1], ov[2], ov[3]);
        if (tid < 128) {
            float s = 0.f;
#pragma unroll
            for (int f = 0; f < 8; f++) s += xsred[f][tid];
            out_segment[(size_t)b * ND + dc * 128 + tid] = s / (float)len;
        }
    }
}

// --------------- out_part[p] = bdh[64,8192] @ w_post chunk p  (split-K KSPL)
__global__ __launch_bounds__(256) void k_post(const float* __restrict__ bdh,
                                              const float* __restrict__ wp,
                                              float* __restrict__ out_part) {
    __shared__ float as[32][68];
    __shared__ float bs[32][128];
    const int tid = threadIdx.x;
    const int n0 = blockIdx.x * 128;
    const int k0 = blockIdx.y * (8192 / KSPL);
    const int tr = tid >> 4, tc = tid & 15;

    float acc[4][8];
#pragma unroll
    for (int i = 0; i < 4; i++)
#pragma unroll
        for (int j = 0; j < 8; j++) acc[i][j] = 0.f;

    for (int kc = 0; kc < 8192 / KSPL; kc += 32) {
        __syncthreads();
        {
            int r = tid >> 2;
            int c = (tid & 3) * 8;
            const float4* gp = (const float4*)(bdh + (size_t)r * (ND * NH) + k0 + kc + c);
            float4 v0 = gp[0], v1 = gp[1];
            as[c + 0][r] = v0.x; as[c + 1][r] = v0.y; as[c + 2][r] = v0.z; as[c + 3][r] = v0.w;
            as[c + 4][r] = v1.x; as[c + 5][r] = v1.y; as[c + 6][r] = v1.z; as[c + 7][r] = v1.w;
        }
        {
            int r = tid >> 3;
            int c = (tid & 7) * 16;
            const float4* gp = (const float4*)(wp + (size_t)(k0 + kc + r) * ND + n0 + c);
            float4* sp = (float4*)&bs[r][c];
            sp[0] = gp[0]; sp[1] = gp[1]; sp[2] = gp[2]; sp[3] = gp[3];
        }
        __syncthreads();
#pragma unroll
        for (int k = 0; k < 32; k++) {
            float4 a  = *(const float4*)&as[k][tr * 4];
            float4 b0 = *(const float4*)&bs[k][tc * 8];
            float4 b1 = *(const float4*)&bs[k][tc * 8 + 4];
            float av[4] = {a.x, a.y, a.z, a.w};
            float bv[8] = {b0.x, b0.y, b0.z, b0.w, b1.x, b1.y, b1.z, b1.w};
#pragma unroll
            for (int i = 0; i < 4; i++)
#pragma unroll
                for (int j = 0; j < 8; j++) acc[i][j] += av[i] * bv[j];
        }
    }

    float* op = out_part + (size_t)blockIdx.y * (NB * ND);
#pragma unroll
    for (int i = 0; i < 4; i++)
#pragma unroll
        for (int j = 0; j < 8; j++)
            op[(size_t)(tr * 4 + i) * ND + n0 + tc * 8 + j] = acc[i][j];
}

// ------------------------------------- out = sum over KSPL k-chunk partials
__global__ __launch_bounds__(256) void k_post_red(const float* __restrict__ out_part,
                                                  float* __restrict__ out) {
    const int i = (blockIdx.x * 256 + threadIdx.x) * 4;
    float4 s = *(const float4*)(out_part + i);
#pragma unroll
    for (int p = 1; p < KSPL; p++) {
        float4 v = *(const float4*)(out_part + (size_t)p * (NB * ND) + i);
        s.x += v.x; s.y += v.y; s.z += v.z; s.w += v.w;
    }
    *(float4*)(out + i) = s;
}

extern "C" void kernel_launch(void* const* d_in, const int* in_sizes, int n_in,
                              void* d_out, int out_size, void* d_ws, size_t ws_size,
                              hipStream_t stream) {
    (void)in_sizes; (void)n_in; (void)out_size; (void)ws_size;
    const float* x      = (const float*)d_in[0];
    const int*   segnum = (const int*)d_in[1];
    const float* w1     = (const float*)d_in[2];
    const float* w2     = (const float*)d_in[3];
    const float* wpost  = (const float*)d_in[4];

    float* out         = (float*)d_out;            // [64*1024]
    float* out_segment = out + NB * ND;            // [64*1024]
    float* gram        = out + 2 * NB * ND;        // [64*64]

    char* ws = (char*)d_ws;
    const size_t MB = 1024 * 1024;
    // layout (peak 64 MB):
    int*   segoff   = (int*)ws;                                    // 1KB   @0
    float* bdh      = (float*)(ws + 2 * MB);                       // 2MB   @2MB
    float* h_part   = (float*)(ws + 4 * MB);                       // 8MB   @4MB
    unsigned short* xb  = (unsigned short*)(ws + 12 * MB);         // 32MB  @12MB
    unsigned short* w1t = (unsigned short*)(ws + 44 * MB);         // 4MB   @44MB
    float* out_part  = (float*)(ws + 48 * MB);                     // 16MB  @48MB

    k_pre<<<10241, 256, 0, stream>>>(x, w1, segnum, xb, w1t, segoff);
    k_c1h<<<dim3(NN / 128, NA / 128), 256, 0, stream>>>(xb, w1t, w2, h_part);
    k_seg<<<dim3(8, NB), 256, 0, stream>>>(h_part, xb, segoff, bdh, out_segment, gram);
    k_post<<<dim3(ND / 128, KSPL), 256, 0, stream>>>(bdh, wpost, out_part);
    k_post_red<<<(NB * ND) / (256 * 4), 256, 0, stream>>>(out_part, out);
}